// Round 7
// baseline (466.923 us; speedup 1.0000x reference)
//
#include <hip/hip_runtime.h>
#include <hip/hip_bf16.h>
#include <hip/hip_fp16.h>

#define HCONC 128   // H*C
#define NHEAD 4
#define CCH   32
#define EDIM  8
#define NREL  16

typedef _Float16 half2_t __attribute__((ext_vector_type(2)));

// ---------------------------------------------------------------------------
// Fused degree + relation histogram. Single pass, int4 loads, 4 independent
// atomic chains per iteration. Grid 2048 blocks -> 32 waves/CU TLP.
// (Round 6's octant version re-read dst 8x and was latency-bound at 8
// waves/CU.)  Self-loops not counted (handled analytically in agg).
__global__ void deghist_kernel(const int* __restrict__ ei, const int* __restrict__ etype,
                               int E, int n, int* __restrict__ deg, int* __restrict__ cnt) {
    __shared__ int lcnt[NREL];
    if (threadIdx.x < NREL) lcnt[threadIdx.x] = 0;
    __syncthreads();
    int tid = blockIdx.x * blockDim.x + threadIdx.x;
    int stride = gridDim.x * blockDim.x;
    int E4 = E >> 2;
    const int4* d4p = (const int4*)(ei + E);
    const int4* t4p = (const int4*)etype;
    for (int i = tid; i < E4; i += stride) {
        int4 d4 = d4p[i];
        int4 t4 = t4p[i];
        atomicAdd(&deg[d4.x], 1);
        atomicAdd(&deg[d4.y], 1);
        atomicAdd(&deg[d4.z], 1);
        atomicAdd(&deg[d4.w], 1);
        atomicAdd(&lcnt[t4.x], 1);
        atomicAdd(&lcnt[t4.y], 1);
        atomicAdd(&lcnt[t4.z], 1);
        atomicAdd(&lcnt[t4.w], 1);
    }
    // tail
    for (int i = (E4 << 2) + tid; i < E; i += stride) {
        atomicAdd(&deg[ei[E + i]], 1);
        atomicAdd(&lcnt[etype[i]], 1);
    }
    __syncthreads();
    if (threadIdx.x < NREL) atomicAdd(&cnt[threadIdx.x], lcnt[threadIdx.x]);
}

// ---------------------------------------------------------------------------
// One-block setup: W0 colsum, mean edge attr, layer-0 score consts, s_edge
// tables, W1 packed to f16x2 (for s_load-uniform MLP weight reads).
__global__ void setup_kernel(const float* __restrict__ W_l0, const float* __restrict__ emb,
                             const int* __restrict__ cnt,
                             const float* __restrict__ att_src, const float* __restrict__ att_dst,
                             const float* __restrict__ att_edge, const float* __restrict__ W_edge,
                             const float* __restrict__ mW1,
                             float* __restrict__ W0s, float* __restrict__ SA0, float* __restrict__ SD0,
                             float* __restrict__ meanat, float* __restrict__ stab,
                             unsigned* __restrict__ W1h, int E) {
    int t = threadIdx.x;
    if (t < HCONC) {
        float s = 0.f;
        for (int k = 0; k < CCH; k++) s += W_l0[k * HCONC + t];
        W0s[t] = s;
    }
    __syncthreads();
    if (t < EDIM) {
        float s = 0.f;
        for (int r = 0; r < NREL; r++) s += (float)cnt[r] * emb[r * EDIM + t];
        meanat[t] = s / (float)E;
    }
    __syncthreads();
    if (t < NHEAD) {
        float sa = 0.f, sd = 0.f;
        for (int c = 0; c < CCH; c++) {
            sa += W0s[t * CCH + c] * att_src[t * CCH + c];
            sd += W0s[t * CCH + c] * att_dst[t * CCH + c];
        }
        SA0[t] = sa; SD0[t] = sd;
    }
    if (t < 3 * 68) {  // 3 layers x 17 types x 4 heads
        int l = t / 68, rem = t % 68, typ = rem >> 2, hh = rem & 3;
        const float* attr = (typ < NREL) ? &emb[typ * EDIM] : meanat;
        const float* We = W_edge + l * EDIM * HCONC;
        const float* ae = att_edge + l * HCONC + hh * CCH;
        float s = 0.f;
        for (int c = 0; c < CCH; c++) {
            float ev = 0.f;
            for (int d = 0; d < EDIM; d++) ev += attr[d] * We[d * HCONC + hh * CCH + c];
            s += ev * ae[c];
        }
        stab[t] = s;  // stab[l*68 + typ*4 + hh]; typ 16 = self-loop (mean attr)
    }
    // W1h[j*64+k2] = half2(W1[2k2][j], W1[2k2+1][j])   (mW1 is [128][100])
    for (int i = t; i < 100 * 64; i += 256) {
        int j = i >> 6, k2 = i & 63;
        __half2 hv = __floats2half2_rn(mW1[(2 * k2) * 100 + j], mW1[(2 * k2 + 1) * 100 + j]);
        W1h[i] = *(unsigned*)&hv;
    }
}

// ---------------------------------------------------------------------------
// CSR scan: block-local scan, single-wave shfl scan of partials, add-back
__global__ void scan1(const int* __restrict__ deg, int n, int* __restrict__ row_ptr,
                      int* __restrict__ partials) {
    __shared__ int tmp[1024];
    int t = threadIdx.x, i = blockIdx.x * 1024 + t;
    int v = (i < n) ? deg[i] : 0;
    tmp[t] = v;
    __syncthreads();
    for (int off = 1; off < 1024; off <<= 1) {
        int add = (t >= off) ? tmp[t - off] : 0;
        __syncthreads();
        tmp[t] += add;
        __syncthreads();
    }
    if (i < n) row_ptr[i] = tmp[t] - v;          // exclusive, block-local
    if (t == 1023) partials[blockIdx.x] = tmp[1023];
}

__global__ void scan2(int* __restrict__ partials, int nb, int* __restrict__ row_ptr, int n) {
    int lane = threadIdx.x;                      // 64 threads, nb <= 64
    int orig = (lane < nb) ? partials[lane] : 0;
    int v = orig;
    for (int off = 1; off < 64; off <<= 1) {
        int t = __shfl_up(v, off);
        if (lane >= off) v += t;
    }
    if (lane < nb) partials[lane] = v - orig;    // exclusive
    if (lane == nb - 1) row_ptr[n] = v;          // total
}

__global__ void scan3(int* __restrict__ row_ptr, int n, const int* __restrict__ partials,
                      int* __restrict__ cursor) {
    int i = blockIdx.x * 1024 + threadIdx.x;
    if (i < n) {
        int r = row_ptr[i] + partials[blockIdx.x];
        row_ptr[i] = r;
        cursor[i] = r;
    }
}

// ---------------------------------------------------------------------------
// Scatter: single pass, int4 coalesced reads, FOUR independent
// atomicAdd->store chains per iteration (MLP), grid 2048 blocks (full TLP).
// Round 5/6 had one chain per thread at 8 waves/CU -> latency-bound 58-67us.
__global__ void scatter_kernel(const int* __restrict__ ei, const int* __restrict__ etype,
                               int E, int n, int* __restrict__ cursor, unsigned* __restrict__ col) {
    int tid = blockIdx.x * blockDim.x + threadIdx.x;
    int stride = gridDim.x * blockDim.x;
    int E4 = E >> 2;
    const int4* d4p = (const int4*)(ei + E);
    const int4* s4p = (const int4*)ei;
    const int4* t4p = (const int4*)etype;
    for (int i = tid; i < E4; i += stride) {
        int4 d4 = d4p[i];
        int4 s4 = s4p[i];
        int4 t4 = t4p[i];
        int p0 = atomicAdd(&cursor[d4.x], 1);
        int p1 = atomicAdd(&cursor[d4.y], 1);
        int p2 = atomicAdd(&cursor[d4.z], 1);
        int p3 = atomicAdd(&cursor[d4.w], 1);
        col[p0] = (unsigned)s4.x | ((unsigned)t4.x << 16);
        col[p1] = (unsigned)s4.y | ((unsigned)t4.y << 16);
        col[p2] = (unsigned)s4.z | ((unsigned)t4.z << 16);
        col[p3] = (unsigned)s4.w | ((unsigned)t4.w << 16);
    }
    // tail
    for (int i = (E4 << 2) + tid; i < E; i += stride) {
        int d = ei[E + i];
        unsigned p = (unsigned)ei[i] | ((unsigned)etype[i] << 16);
        int pos = atomicAdd(&cursor[d], 1);
        col[pos] = p;
    }
}

// ---------------------------------------------------------------------------
// Layer-0 rank-1 transform (fused h + scores): h0 = x * colsum(W0)
__global__ void l0_kernel(const float* __restrict__ x, const float* __restrict__ W0s,
                          const float* __restrict__ SA0, const float* __restrict__ SD0,
                          __hip_bfloat162* __restrict__ h, float* __restrict__ s_src,
                          float* __restrict__ s_dst, int n) {
    int idx = blockIdx.x * blockDim.x + threadIdx.x;
    if (idx < n * 64) {
        int row = idx >> 6, c = idx & 63;
        float xv = x[row];
        float2 w = ((const float2*)W0s)[c];
        __hip_bfloat162 hv;
        hv.x = __float2bfloat16(xv * w.x);
        hv.y = __float2bfloat16(xv * w.y);
        h[idx] = hv;
        if (c < 4) {
            s_src[row * 4 + c] = xv * SA0[c];
            s_dst[row * 4 + c] = xv * SD0[c];
        }
    }
}

// ---------------------------------------------------------------------------
// Dense transform h = X @ W (128x128) + fused attention score reduction.
// X tile (32 rows) staged in LDS; lane owns col pair (2L,2L+1); W read as
// float2.  NO min-waves bound (round 2: (256,4) capped VGPR at 64 -> spill).
__global__ __launch_bounds__(256) void transform_kernel(
    const float* __restrict__ X, const float* __restrict__ W,
    const float* __restrict__ a_src, const float* __restrict__ a_dst,
    __hip_bfloat162* __restrict__ h_out, float* __restrict__ s_src,
    float* __restrict__ s_dst, int n) {
    __shared__ float xs[32][HCONC];  // 16 KB
    int tid = threadIdx.x;
    int row_blk = blockIdx.x * 32;

    // stage X tile (coalesced float4)
    const float4* Xg = (const float4*)X;
#pragma unroll
    for (int i = 0; i < 4; i++) {
        int f = tid + i * 256;                  // float4 index in tile (32x32)
        int rloc = f >> 5, c4 = f & 31;
        int grow = row_blk + rloc;
        float4 v = (grow < n) ? Xg[(size_t)grow * 32 + c4] : make_float4(0.f, 0.f, 0.f, 0.f);
        ((float4*)xs)[f] = v;
    }
    __syncthreads();

    int lane = tid & 63;
    int wv = tid >> 6;

    float acc0[8], acc1[8];
#pragma unroll
    for (int r = 0; r < 8; r++) { acc0[r] = 0.f; acc1[r] = 0.f; }

    const float2* W2p = (const float2*)W;
    for (int k4 = 0; k4 < 32; k4++) {
        float2 w0 = W2p[(k4 * 4 + 0) * 64 + lane];
        float2 w1 = W2p[(k4 * 4 + 1) * 64 + lane];
        float2 w2 = W2p[(k4 * 4 + 2) * 64 + lane];
        float2 w3 = W2p[(k4 * 4 + 3) * 64 + lane];
#pragma unroll
        for (int r = 0; r < 8; r++) {
            float4 xv = *(const float4*)&xs[wv * 8 + r][k4 * 4];
            acc0[r] = fmaf(xv.x, w0.x, acc0[r]);
            acc1[r] = fmaf(xv.x, w0.y, acc1[r]);
            acc0[r] = fmaf(xv.y, w1.x, acc0[r]);
            acc1[r] = fmaf(xv.y, w1.y, acc1[r]);
            acc0[r] = fmaf(xv.z, w2.x, acc0[r]);
            acc1[r] = fmaf(xv.z, w2.y, acc1[r]);
            acc0[r] = fmaf(xv.w, w3.x, acc0[r]);
            acc1[r] = fmaf(xv.w, w3.y, acc1[r]);
        }
    }

    float2 as2 = ((const float2*)a_src)[lane];
    float2 ad2 = ((const float2*)a_dst)[lane];

#pragma unroll
    for (int r = 0; r < 8; r++) {
        int row = row_blk + wv * 8 + r;
        float ts = acc0[r] * as2.x + acc1[r] * as2.y;
        float td = acc0[r] * ad2.x + acc1[r] * ad2.y;
#pragma unroll
        for (int off = 1; off <= 8; off <<= 1) {
            ts += __shfl_xor(ts, off);
            td += __shfl_xor(td, off);
        }
        if (row < n) {
            __hip_bfloat162 hv;
            hv.x = __float2bfloat16(acc0[r]);
            hv.y = __float2bfloat16(acc1[r]);
            h_out[(size_t)row * 64 + lane] = hv;
            if ((lane & 15) == 0) {
                s_src[row * 4 + (lane >> 4)] = ts;
                s_dst[row * 4 + (lane >> 4)] = td;
            }
        }
    }
}

// ---------------------------------------------------------------------------
// Softmax-aggregation: one wave per dst node, online softmax, FOUR parallel
// edge streams per wave (16 lanes each; lane owns 8 channels).  Self-loop
// handled analytically: stream 0 initializes with (s_self, h[d]); col holds
// only real edges.  All-padded streams are zeroed in the merge (fB=0).
__global__ __launch_bounds__(256) void agg_kernel(
    const unsigned* __restrict__ h,     // bf16x2 per uint, [n][64]
    const float* __restrict__ s_src, const float* __restrict__ s_dst,
    const int* __restrict__ row_ptr, const unsigned* __restrict__ col,
    const float* __restrict__ tab, const float* __restrict__ bias,
    const float* __restrict__ x_prev, float* __restrict__ x_out, int n) {
    __shared__ float stab_s[68];
    if (threadIdx.x < 68) stab_s[threadIdx.x] = tab[threadIdx.x];
    __syncthreads();

    int d = __builtin_amdgcn_readfirstlane(blockIdx.x * 4 + (threadIdx.x >> 6));
    if (d >= n) return;
    int lane = threadIdx.x & 63;
    int strm = lane >> 4;             // 0..3
    int l16 = lane & 15;              // channel group within row
    int head = l16 >> 2;              // 16 lanes cover 128 ch; 4 lanes/head

    int start = row_ptr[d], end = row_ptr[d + 1];
    int L = end - start;
    int q = (L + 3) >> 2;             // trips (wave-uniform)
    int gs = start + strm * q;
    int len = min(q, max(0, end - gs));

    float sdh = s_dst[d * 4 + head];

    float m = -1e30f, den = 0.f;
    float a0 = 0.f, a1 = 0.f, a2 = 0.f, a3 = 0.f;
    float a4 = 0.f, a5 = 0.f, a6 = 0.f, a7 = 0.f;

    if (strm == 0) {                  // self edge (typ=16, mean attr)
        float s = s_src[d * 4 + head] + sdh + stab_s[64 + head];
        s = s > 0.f ? s : 0.2f * s;
        uint4 u = *(const uint4*)(h + d * 64 + 4 * l16);
        m = s; den = 1.f;
        a0 = __uint_as_float(u.x << 16);  a1 = __uint_as_float(u.x & 0xFFFF0000u);
        a2 = __uint_as_float(u.y << 16);  a3 = __uint_as_float(u.y & 0xFFFF0000u);
        a4 = __uint_as_float(u.z << 16);  a5 = __uint_as_float(u.z & 0xFFFF0000u);
        a6 = __uint_as_float(u.w << 16);  a7 = __uint_as_float(u.w & 0xFFFF0000u);
    }

    if (L > 0) {
        int idx0 = gs < end ? gs : end - 1;
        unsigned p = col[idx0];
        for (int i = 0; i < q; i++) {
            int ni = gs + i + 1;
            if (ni > end - 1) ni = end - 1;
            unsigned pn = col[ni];                // prefetch next packed edge
            int src = (int)(p & 0xFFFFu);
            int typ = (int)(p >> 16);
            const uint4* hp = (const uint4*)(h + src * 64 + 4 * l16);
            uint4 u = *hp;                        // 8 bf16 channels
            float s = s_src[src * 4 + head] + sdh + stab_s[typ * 4 + head];
            s = s > 0.f ? s : 0.2f * s;
            if (i >= len) s = -1e30f;             // padding iter -> weight 0
            float mn = fmaxf(m, s);
            float w = __expf(s - mn);
            float sc = __expf(m - mn);
            den = den * sc + w;
            a0 = fmaf(w, __uint_as_float(u.x << 16),          a0 * sc);
            a1 = fmaf(w, __uint_as_float(u.x & 0xFFFF0000u),  a1 * sc);
            a2 = fmaf(w, __uint_as_float(u.y << 16),          a2 * sc);
            a3 = fmaf(w, __uint_as_float(u.y & 0xFFFF0000u),  a3 * sc);
            a4 = fmaf(w, __uint_as_float(u.z << 16),          a4 * sc);
            a5 = fmaf(w, __uint_as_float(u.z & 0xFFFF0000u),  a5 * sc);
            a6 = fmaf(w, __uint_as_float(u.w << 16),          a6 * sc);
            a7 = fmaf(w, __uint_as_float(u.w & 0xFFFF0000u),  a7 * sc);
            m = mn;
            p = pn;
        }
    }

    // merge 4 streams: xor16 then xor32
#pragma unroll
    for (int off = 16; off <= 32; off <<= 1) {
        float om  = __shfl_xor(m, off);
        float oden = __shfl_xor(den, off);
        float o0 = __shfl_xor(a0, off), o1 = __shfl_xor(a1, off);
        float o2 = __shfl_xor(a2, off), o3 = __shfl_xor(a3, off);
        float o4 = __shfl_xor(a4, off), o5 = __shfl_xor(a5, off);
        float o6 = __shfl_xor(a6, off), o7 = __shfl_xor(a7, off);
        float M = fmaxf(m, om);
        float fA = __expf(m - M), fB = __expf(om - M);
        den = den * fA + oden * fB;
        a0 = a0 * fA + o0 * fB;  a1 = a1 * fA + o1 * fB;
        a2 = a2 * fA + o2 * fB;  a3 = a3 * fA + o3 * fB;
        a4 = a4 * fA + o4 * fB;  a5 = a5 * fA + o5 * fB;
        a6 = a6 * fA + o6 * fB;  a7 = a7 * fA + o7 * fB;
        m = M;
    }

    if (lane < 16) {
        float inv = 1.f / (den + 1e-16f);
        float4 b0 = ((const float4*)bias)[2 * l16];
        float4 b1v = ((const float4*)bias)[2 * l16 + 1];
        float4 o0v, o1v;
        o0v.x = a0 * inv + b0.x;  o0v.y = a1 * inv + b0.y;
        o0v.z = a2 * inv + b0.z;  o0v.w = a3 * inv + b0.w;
        o1v.x = a4 * inv + b1v.x; o1v.y = a5 * inv + b1v.y;
        o1v.z = a6 * inv + b1v.z; o1v.w = a7 * inv + b1v.w;
        if (x_prev) {
            float4 p0 = ((const float4*)x_prev)[(size_t)d * 32 + 2 * l16];
            float4 p1 = ((const float4*)x_prev)[(size_t)d * 32 + 2 * l16 + 1];
            o0v.x += p0.x; o0v.y += p0.y; o0v.z += p0.z; o0v.w += p0.w;
            o1v.x += p1.x; o1v.y += p1.y; o1v.z += p1.z; o1v.w += p1.w;
        }
        o0v.x = fmaxf(o0v.x, 0.f); o0v.y = fmaxf(o0v.y, 0.f);
        o0v.z = fmaxf(o0v.z, 0.f); o0v.w = fmaxf(o0v.w, 0.f);
        o1v.x = fmaxf(o1v.x, 0.f); o1v.y = fmaxf(o1v.y, 0.f);
        o1v.w = fmaxf(o1v.w, 0.f); o1v.z = fmaxf(o1v.z, 0.f);
        ((float4*)x_out)[(size_t)d * 32 + 2 * l16]     = o0v;
        ((float4*)x_out)[(size_t)d * 32 + 2 * l16 + 1] = o1v;
    }
}

// ---------------------------------------------------------------------------
// MLP head: thread-per-node; x row held as 64 f16x2 regs, W1 pre-packed f16x2
// read wave-uniform (s_load).  v_dot2_f32_f16 with 4 accumulator chains.
__global__ __launch_bounds__(64) void mlp_kernel(
    const float* __restrict__ X, const unsigned* __restrict__ W1h,
    const float* __restrict__ b1, const float* __restrict__ W2,
    const float* __restrict__ b2, float* __restrict__ out, int n) {
    int node = blockIdx.x * 64 + threadIdx.x;
    int r = node < n ? node : n - 1;

    unsigned xh[64];
    const float2* xp = (const float2*)(X + (size_t)r * HCONC);
#pragma unroll
    for (int k2 = 0; k2 < 64; k2++) {
        float2 v = xp[k2];
        __half2 hv = __floats2half2_rn(v.x, v.y);
        xh[k2] = *(unsigned*)&hv;
    }

    float total = b2[0];
    for (int j = 0; j < 100; j++) {
        const unsigned* wr = W1h + j * 64;        // wave-uniform -> s_load
        float p0 = b1[j], p1 = 0.f, p2 = 0.f, p3 = 0.f;
#pragma unroll
        for (int k2 = 0; k2 < 64; k2 += 4) {
            half2_t x0 = __builtin_bit_cast(half2_t, xh[k2 + 0]);
            half2_t x1 = __builtin_bit_cast(half2_t, xh[k2 + 1]);
            half2_t x2 = __builtin_bit_cast(half2_t, xh[k2 + 2]);
            half2_t x3 = __builtin_bit_cast(half2_t, xh[k2 + 3]);
            half2_t w0 = __builtin_bit_cast(half2_t, wr[k2 + 0]);
            half2_t w1 = __builtin_bit_cast(half2_t, wr[k2 + 1]);
            half2_t w2 = __builtin_bit_cast(half2_t, wr[k2 + 2]);
            half2_t w3 = __builtin_bit_cast(half2_t, wr[k2 + 3]);
#if __has_builtin(__builtin_amdgcn_fdot2)
            p0 = __builtin_amdgcn_fdot2(x0, w0, p0, false);
            p1 = __builtin_amdgcn_fdot2(x1, w1, p1, false);
            p2 = __builtin_amdgcn_fdot2(x2, w2, p2, false);
            p3 = __builtin_amdgcn_fdot2(x3, w3, p3, false);
#else
            p0 = fmaf((float)x0[0], (float)w0[0], fmaf((float)x0[1], (float)w0[1], p0));
            p1 = fmaf((float)x1[0], (float)w1[0], fmaf((float)x1[1], (float)w1[1], p1));
            p2 = fmaf((float)x2[0], (float)w2[0], fmaf((float)x2[1], (float)w2[1], p2));
            p3 = fmaf((float)x3[0], (float)w3[0], fmaf((float)x3[1], (float)w3[1], p3));
#endif
        }
        float a = (p0 + p1) + (p2 + p3);
        total = fmaf(fmaxf(a, 0.f), W2[j], total);
    }
    if (node < n) out[node] = 1.f / (1.f + __expf(-total));
}

// ---------------------------------------------------------------------------
extern "C" void kernel_launch(void* const* d_in, const int* in_sizes, int n_in,
                              void* d_out, int out_size, void* d_ws, size_t ws_size,
                              hipStream_t stream) {
    const float* x       = (const float*)d_in[0];
    const int*   ei      = (const int*)d_in[1];     // [2,E]: src then dst
    const int*   etype   = (const int*)d_in[2];
    const float* emb     = (const float*)d_in[3];   // [16,8]
    const float* W_l0    = (const float*)d_in[4];   // [32,128]
    const float* W_l1    = (const float*)d_in[5];   // [128,128]
    const float* W_l2    = (const float*)d_in[6];   // [128,128]
    const float* att_src = (const float*)d_in[7];   // [3,4,32]
    const float* att_dst = (const float*)d_in[8];
    const float* att_edge= (const float*)d_in[9];
    const float* W_edge  = (const float*)d_in[10];  // [3,8,128]
    const float* bias    = (const float*)d_in[11];  // [3,128]
    const float* mW1     = (const float*)d_in[12];  // [128,100]
    const float* mb1     = (const float*)d_in[13];
    const float* mW2     = (const float*)d_in[14];  // [100,1]
    const float* mb2     = (const float*)d_in[15];

    int n = in_sizes[0];   // 50000
    int E = in_sizes[2];   // 800000

    // workspace carve
    float* p   = (float*)d_ws;
    float* xa  = p; p += (size_t)n * HCONC;
    float* xb  = p; p += (size_t)n * HCONC;
    float* ssrc = p; p += (size_t)n * NHEAD;
    float* sdst = p; p += (size_t)n * NHEAD;
    float* hbf  = p; p += (size_t)n * 64;          // bf16x2 h buffer (n*128 bf16)
    unsigned* W1h = (unsigned*)p; p += 100 * 64;   // f16x2-packed W1^T
    int* deg      = (int*)p;
    int* row_ptr  = deg + n;
    int* cursor   = row_ptr + n + 1;
    int* partials = cursor + n;      // 64
    int* cnt      = partials + 64;   // 16
    float* W0s    = (float*)(cnt + 16);
    float* SA0    = W0s + HCONC;
    float* SD0    = SA0 + NHEAD;
    float* meanat = SD0 + NHEAD;
    float* stab   = meanat + EDIM;   // 3*68 = 204, round to 256
    unsigned* col = (unsigned*)(stab + 256);  // E entries (no self loops)

    // zero the metadata region (deg..cnt) — ws is poisoned 0xAA by harness
    size_t zero_bytes = (size_t)((char*)(cnt + 16) - (char*)deg);
    hipMemsetAsync(deg, 0, zero_bytes, stream);

    deghist_kernel<<<2048, 256, 0, stream>>>(ei, etype, E, n, deg, cnt);
    setup_kernel<<<1, 256, 0, stream>>>(W_l0, emb, cnt, att_src, att_dst, att_edge, W_edge,
                                        mW1, W0s, SA0, SD0, meanat, stab, W1h, E);
    int nb_scan = (n + 1023) / 1024;
    scan1<<<nb_scan, 1024, 0, stream>>>(deg, n, row_ptr, partials);
    scan2<<<1, 64, 0, stream>>>(partials, nb_scan, row_ptr, n);
    scan3<<<nb_scan, 1024, 0, stream>>>(row_ptr, n, partials, cursor);
    scatter_kernel<<<2048, 256, 0, stream>>>(ei, etype, E, n, cursor, col);

    // layer 0 (rank-1 input)
    l0_kernel<<<(n * 64 + 255) / 256, 256, 0, stream>>>(x, W0s, SA0, SD0,
                                                        (__hip_bfloat162*)hbf, ssrc, sdst, n);
    agg_kernel<<<(n + 3) / 4, 256, 0, stream>>>((const unsigned*)hbf, ssrc, sdst, row_ptr, col,
                                                stab + 0, bias + 0, nullptr, xa, n);
    // layer 1
    transform_kernel<<<(n + 31) / 32, 256, 0, stream>>>(xa, W_l1, att_src + 128, att_dst + 128,
                                                        (__hip_bfloat162*)hbf, ssrc, sdst, n);
    agg_kernel<<<(n + 3) / 4, 256, 0, stream>>>((const unsigned*)hbf, ssrc, sdst, row_ptr, col,
                                                stab + 68, bias + 128, xa, xb, n);
    // layer 2
    transform_kernel<<<(n + 31) / 32, 256, 0, stream>>>(xb, W_l2, att_src + 256, att_dst + 256,
                                                        (__hip_bfloat162*)hbf, ssrc, sdst, n);
    agg_kernel<<<(n + 3) / 4, 256, 0, stream>>>((const unsigned*)hbf, ssrc, sdst, row_ptr, col,
                                                stab + 136, bias + 256, xb, xa, n);
    // MLP head
    mlp_kernel<<<(n + 63) / 64, 64, 0, stream>>>(xa, W1h, mb1, mW2, mb2, (float*)d_out, n);
}

// Round 8
// 388.652 us; speedup vs baseline: 1.2014x; 1.2014x over previous
//
#include <hip/hip_runtime.h>
#include <hip/hip_bf16.h>
#include <hip/hip_fp16.h>

#define HCONC 128   // H*C
#define NHEAD 4
#define CCH   32
#define EDIM  8
#define NREL  16
#define BCAP  5120  // per-bucket capacity (mean ~4081, +16 sigma headroom)
#define TILE  2048  // edges per binA block

typedef _Float16 half2_t __attribute__((ext_vector_type(2)));

// ---------------------------------------------------------------------------
// init: per-bucket global cursors to fixed-capacity region starts; zero cnt.
__global__ void init_kernel(int* __restrict__ gcursor, int* __restrict__ cnt, int nbuk) {
    int t = threadIdx.x;
    if (t < nbuk) gcursor[t] = t * BCAP;
    if (t < NREL) cnt[t] = 0;
}

// ---------------------------------------------------------------------------
// binA: tile-local counting sort by dst-bucket (bucket = dst>>8), coalesced
// run writes into per-bucket regions of ebuf.  Replaces deghist's histogram
// (relation counts accumulated here).  All global writes are contiguous runs
// — fixes round 5/6/7's 52 MB one-line-per-edge write amplification.
__global__ __launch_bounds__(256) void binA_kernel(
    const int* __restrict__ ei, const int* __restrict__ etype, int E, int nbuk,
    int* __restrict__ gcursor, int* __restrict__ cnt, uint2* __restrict__ ebuf) {
    __shared__ int hist[256], lbase[256], gbase[256], tmp[256];
    __shared__ int lcnt16[NREL];
    __shared__ uint2 srt[TILE];
    int t = threadIdx.x;
    hist[t] = 0;
    if (t < NREL) lcnt16[t] = 0;
    __syncthreads();

    int base = blockIdx.x * TILE;
    int count = min(TILE, E - base);

    uint2 rec[8]; int slot[8]; int buk[8];
#pragma unroll
    for (int i = 0; i < 8; i++) {
        int idx = t + i * 256;
        if (idx < count) {
            int g = base + idx;
            int s = ei[g], d = ei[E + g], ty = etype[g];
            rec[i].x = (unsigned)s | ((unsigned)ty << 16);
            rec[i].y = (unsigned)d;
            buk[i] = d >> 8;
            slot[i] = atomicAdd(&hist[buk[i]], 1);
            atomicAdd(&lcnt16[ty], 1);
        } else buk[i] = -1;
    }
    __syncthreads();

    // exclusive scan of hist (Hillis-Steele, 256 wide)
    int v = hist[t];
    tmp[t] = v; __syncthreads();
    for (int off = 1; off < 256; off <<= 1) {
        int add = (t >= off) ? tmp[t - off] : 0; __syncthreads();
        tmp[t] += add; __syncthreads();
    }
    lbase[t] = tmp[t] - v;
    if (t < nbuk && v > 0) gbase[t] = atomicAdd(&gcursor[t], v);  // reserve run
    __syncthreads();

    // scatter into bucket-sorted LDS order (LDS: no write amplification)
#pragma unroll
    for (int i = 0; i < 8; i++)
        if (buk[i] >= 0) srt[lbase[buk[i]] + slot[i]] = rec[i];
    if (t < NREL) atomicAdd(&cnt[t], lcnt16[t]);
    __syncthreads();

    // coalesced run copy-out
    for (int idx = t; idx < count; idx += 256) {
        uint2 r = srt[idx];
        int b = (int)(r.y >> 8);
        int gpos = gbase[b] + idx - lbase[b];
        if (gpos < (b + 1) * BCAP) ebuf[gpos] = r;   // cap guard (never trips)
    }
}

// ---------------------------------------------------------------------------
// bscan: exclusive scan of bucket counts -> bucket_base; writes row_ptr[n].
__global__ void bscan_kernel(const int* __restrict__ gcursor, int nbuk,
                             int* __restrict__ bucket_base, int* __restrict__ row_ptr, int n) {
    __shared__ int tmp[256];
    int t = threadIdx.x;
    int v = (t < nbuk) ? (gcursor[t] - t * BCAP) : 0;
    tmp[t] = v; __syncthreads();
    for (int off = 1; off < 256; off <<= 1) {
        int add = (t >= off) ? tmp[t - off] : 0; __syncthreads();
        tmp[t] += add; __syncthreads();
    }
    if (t < nbuk) bucket_base[t] = tmp[t] - v;
    if (t == nbuk - 1) { bucket_base[nbuk] = tmp[t]; row_ptr[n] = tmp[t]; }
}

// ---------------------------------------------------------------------------
// binB: per-bucket fine sort.  Per-dst histogram + scan writes row_ptr for
// the bucket's <=256 dsts (replaces scan1/scan3 over 50k); LDS scatter of
// src|typ into a col slice; one fully-coalesced dump to global col.
__global__ __launch_bounds__(256) void binB_kernel(
    const uint2* __restrict__ ebuf, const int* __restrict__ gcursor,
    const int* __restrict__ bucket_base, int n,
    int* __restrict__ row_ptr, unsigned* __restrict__ col) {
    __shared__ int hist[256], lcur[256], lbase[256], tmp[256];
    __shared__ unsigned colsl[BCAP];   // 20 KB
    int b = blockIdx.x, t = threadIdx.x;
    int base = b * BCAP;
    int cntb = min(gcursor[b] - base, BCAP);
    int gstart = bucket_base[b];
    hist[t] = 0;
    __syncthreads();
    for (int i = t; i < cntb; i += 256) {
        uint2 r = ebuf[base + i];
        atomicAdd(&hist[r.y & 255], 1);
    }
    __syncthreads();
    int v = hist[t];
    tmp[t] = v; __syncthreads();
    for (int off = 1; off < 256; off <<= 1) {
        int add = (t >= off) ? tmp[t - off] : 0; __syncthreads();
        tmp[t] += add; __syncthreads();
    }
    lbase[t] = tmp[t] - v;
    lcur[t] = tmp[t] - v;
    int gdst = (b << 8) + t;
    if (gdst < n) row_ptr[gdst] = gstart + tmp[t] - v;
    __syncthreads();
    for (int i = t; i < cntb; i += 256) {
        uint2 r = ebuf[base + i];
        int pos = atomicAdd(&lcur[r.y & 255], 1);
        colsl[pos] = r.x;
    }
    __syncthreads();
    for (int i = t; i < cntb; i += 256)
        col[gstart + i] = colsl[i];
}

// ---------------------------------------------------------------------------
// One-block setup: W0 colsum, mean edge attr, layer-0 score consts, s_edge
// tables, W1 packed to f16x2 (for s_load-uniform MLP weight reads).
__global__ void setup_kernel(const float* __restrict__ W_l0, const float* __restrict__ emb,
                             const int* __restrict__ cnt,
                             const float* __restrict__ att_src, const float* __restrict__ att_dst,
                             const float* __restrict__ att_edge, const float* __restrict__ W_edge,
                             const float* __restrict__ mW1,
                             float* __restrict__ W0s, float* __restrict__ SA0, float* __restrict__ SD0,
                             float* __restrict__ meanat, float* __restrict__ stab,
                             unsigned* __restrict__ W1h, int E) {
    int t = threadIdx.x;
    if (t < HCONC) {
        float s = 0.f;
        for (int k = 0; k < CCH; k++) s += W_l0[k * HCONC + t];
        W0s[t] = s;
    }
    __syncthreads();
    if (t < EDIM) {
        float s = 0.f;
        for (int r = 0; r < NREL; r++) s += (float)cnt[r] * emb[r * EDIM + t];
        meanat[t] = s / (float)E;
    }
    __syncthreads();
    if (t < NHEAD) {
        float sa = 0.f, sd = 0.f;
        for (int c = 0; c < CCH; c++) {
            sa += W0s[t * CCH + c] * att_src[t * CCH + c];
            sd += W0s[t * CCH + c] * att_dst[t * CCH + c];
        }
        SA0[t] = sa; SD0[t] = sd;
    }
    if (t < 3 * 68) {  // 3 layers x 17 types x 4 heads
        int l = t / 68, rem = t % 68, typ = rem >> 2, hh = rem & 3;
        const float* attr = (typ < NREL) ? &emb[typ * EDIM] : meanat;
        const float* We = W_edge + l * EDIM * HCONC;
        const float* ae = att_edge + l * HCONC + hh * CCH;
        float s = 0.f;
        for (int c = 0; c < CCH; c++) {
            float ev = 0.f;
            for (int d = 0; d < EDIM; d++) ev += attr[d] * We[d * HCONC + hh * CCH + c];
            s += ev * ae[c];
        }
        stab[t] = s;  // stab[l*68 + typ*4 + hh]; typ 16 = self-loop (mean attr)
    }
    // W1h[j*64+k2] = half2(W1[2k2][j], W1[2k2+1][j])   (mW1 is [128][100])
    for (int i = t; i < 100 * 64; i += 256) {
        int j = i >> 6, k2 = i & 63;
        __half2 hv = __floats2half2_rn(mW1[(2 * k2) * 100 + j], mW1[(2 * k2 + 1) * 100 + j]);
        W1h[i] = *(unsigned*)&hv;
    }
}

// ---------------------------------------------------------------------------
// Layer-0 rank-1 transform (fused h + scores): h0 = x * colsum(W0)
__global__ void l0_kernel(const float* __restrict__ x, const float* __restrict__ W0s,
                          const float* __restrict__ SA0, const float* __restrict__ SD0,
                          __hip_bfloat162* __restrict__ h, float* __restrict__ s_src,
                          float* __restrict__ s_dst, int n) {
    int idx = blockIdx.x * blockDim.x + threadIdx.x;
    if (idx < n * 64) {
        int row = idx >> 6, c = idx & 63;
        float xv = x[row];
        float2 w = ((const float2*)W0s)[c];
        __hip_bfloat162 hv;
        hv.x = __float2bfloat16(xv * w.x);
        hv.y = __float2bfloat16(xv * w.y);
        h[idx] = hv;
        if (c < 4) {
            s_src[row * 4 + c] = xv * SA0[c];
            s_dst[row * 4 + c] = xv * SD0[c];
        }
    }
}

// ---------------------------------------------------------------------------
// Dense transform h = X @ W (128x128) + fused attention score reduction.
// X tile (32 rows) staged in LDS; lane owns col pair (2L,2L+1); W read as
// float2.  NO min-waves bound (round 2: (256,4) capped VGPR at 64 -> spill).
__global__ __launch_bounds__(256) void transform_kernel(
    const float* __restrict__ X, const float* __restrict__ W,
    const float* __restrict__ a_src, const float* __restrict__ a_dst,
    __hip_bfloat162* __restrict__ h_out, float* __restrict__ s_src,
    float* __restrict__ s_dst, int n) {
    __shared__ float xs[32][HCONC];  // 16 KB
    int tid = threadIdx.x;
    int row_blk = blockIdx.x * 32;

    // stage X tile (coalesced float4)
    const float4* Xg = (const float4*)X;
#pragma unroll
    for (int i = 0; i < 4; i++) {
        int f = tid + i * 256;                  // float4 index in tile (32x32)
        int rloc = f >> 5, c4 = f & 31;
        int grow = row_blk + rloc;
        float4 v = (grow < n) ? Xg[(size_t)grow * 32 + c4] : make_float4(0.f, 0.f, 0.f, 0.f);
        ((float4*)xs)[f] = v;
    }
    __syncthreads();

    int lane = tid & 63;
    int wv = tid >> 6;

    float acc0[8], acc1[8];
#pragma unroll
    for (int r = 0; r < 8; r++) { acc0[r] = 0.f; acc1[r] = 0.f; }

    const float2* W2p = (const float2*)W;
    for (int k4 = 0; k4 < 32; k4++) {
        float2 w0 = W2p[(k4 * 4 + 0) * 64 + lane];
        float2 w1 = W2p[(k4 * 4 + 1) * 64 + lane];
        float2 w2 = W2p[(k4 * 4 + 2) * 64 + lane];
        float2 w3 = W2p[(k4 * 4 + 3) * 64 + lane];
#pragma unroll
        for (int r = 0; r < 8; r++) {
            float4 xv = *(const float4*)&xs[wv * 8 + r][k4 * 4];
            acc0[r] = fmaf(xv.x, w0.x, acc0[r]);
            acc1[r] = fmaf(xv.x, w0.y, acc1[r]);
            acc0[r] = fmaf(xv.y, w1.x, acc0[r]);
            acc1[r] = fmaf(xv.y, w1.y, acc1[r]);
            acc0[r] = fmaf(xv.z, w2.x, acc0[r]);
            acc1[r] = fmaf(xv.z, w2.y, acc1[r]);
            acc0[r] = fmaf(xv.w, w3.x, acc0[r]);
            acc1[r] = fmaf(xv.w, w3.y, acc1[r]);
        }
    }

    float2 as2 = ((const float2*)a_src)[lane];
    float2 ad2 = ((const float2*)a_dst)[lane];

#pragma unroll
    for (int r = 0; r < 8; r++) {
        int row = row_blk + wv * 8 + r;
        float ts = acc0[r] * as2.x + acc1[r] * as2.y;
        float td = acc0[r] * ad2.x + acc1[r] * ad2.y;
#pragma unroll
        for (int off = 1; off <= 8; off <<= 1) {
            ts += __shfl_xor(ts, off);
            td += __shfl_xor(td, off);
        }
        if (row < n) {
            __hip_bfloat162 hv;
            hv.x = __float2bfloat16(acc0[r]);
            hv.y = __float2bfloat16(acc1[r]);
            h_out[(size_t)row * 64 + lane] = hv;
            if ((lane & 15) == 0) {
                s_src[row * 4 + (lane >> 4)] = ts;
                s_dst[row * 4 + (lane >> 4)] = td;
            }
        }
    }
}

// ---------------------------------------------------------------------------
// Softmax-aggregation: one wave per dst node, online softmax, FOUR parallel
// edge streams per wave (16 lanes each; lane owns 8 channels).  Self-loop
// handled analytically: stream 0 initializes with (s_self, h[d]); col holds
// only real edges.  All-padded streams are zeroed in the merge (fB=0).
__global__ __launch_bounds__(256) void agg_kernel(
    const unsigned* __restrict__ h,     // bf16x2 per uint, [n][64]
    const float* __restrict__ s_src, const float* __restrict__ s_dst,
    const int* __restrict__ row_ptr, const unsigned* __restrict__ col,
    const float* __restrict__ tab, const float* __restrict__ bias,
    const float* __restrict__ x_prev, float* __restrict__ x_out, int n) {
    __shared__ float stab_s[68];
    if (threadIdx.x < 68) stab_s[threadIdx.x] = tab[threadIdx.x];
    __syncthreads();

    int d = __builtin_amdgcn_readfirstlane(blockIdx.x * 4 + (threadIdx.x >> 6));
    if (d >= n) return;
    int lane = threadIdx.x & 63;
    int strm = lane >> 4;             // 0..3
    int l16 = lane & 15;              // channel group within row
    int head = l16 >> 2;              // 16 lanes cover 128 ch; 4 lanes/head

    int start = row_ptr[d], end = row_ptr[d + 1];
    int L = end - start;
    int q = (L + 3) >> 2;             // trips (wave-uniform)
    int gs = start + strm * q;
    int len = min(q, max(0, end - gs));

    float sdh = s_dst[d * 4 + head];

    float m = -1e30f, den = 0.f;
    float a0 = 0.f, a1 = 0.f, a2 = 0.f, a3 = 0.f;
    float a4 = 0.f, a5 = 0.f, a6 = 0.f, a7 = 0.f;

    if (strm == 0) {                  // self edge (typ=16, mean attr)
        float s = s_src[d * 4 + head] + sdh + stab_s[64 + head];
        s = s > 0.f ? s : 0.2f * s;
        uint4 u = *(const uint4*)(h + d * 64 + 4 * l16);
        m = s; den = 1.f;
        a0 = __uint_as_float(u.x << 16);  a1 = __uint_as_float(u.x & 0xFFFF0000u);
        a2 = __uint_as_float(u.y << 16);  a3 = __uint_as_float(u.y & 0xFFFF0000u);
        a4 = __uint_as_float(u.z << 16);  a5 = __uint_as_float(u.z & 0xFFFF0000u);
        a6 = __uint_as_float(u.w << 16);  a7 = __uint_as_float(u.w & 0xFFFF0000u);
    }

    if (L > 0) {
        int idx0 = gs < end ? gs : end - 1;
        unsigned p = col[idx0];
        for (int i = 0; i < q; i++) {
            int ni = gs + i + 1;
            if (ni > end - 1) ni = end - 1;
            unsigned pn = col[ni];                // prefetch next packed edge
            int src = (int)(p & 0xFFFFu);
            int typ = (int)(p >> 16);
            const uint4* hp = (const uint4*)(h + src * 64 + 4 * l16);
            uint4 u = *hp;                        // 8 bf16 channels
            float s = s_src[src * 4 + head] + sdh + stab_s[typ * 4 + head];
            s = s > 0.f ? s : 0.2f * s;
            if (i >= len) s = -1e30f;             // padding iter -> weight 0
            float mn = fmaxf(m, s);
            float w = __expf(s - mn);
            float sc = __expf(m - mn);
            den = den * sc + w;
            a0 = fmaf(w, __uint_as_float(u.x << 16),          a0 * sc);
            a1 = fmaf(w, __uint_as_float(u.x & 0xFFFF0000u),  a1 * sc);
            a2 = fmaf(w, __uint_as_float(u.y << 16),          a2 * sc);
            a3 = fmaf(w, __uint_as_float(u.y & 0xFFFF0000u),  a3 * sc);
            a4 = fmaf(w, __uint_as_float(u.z << 16),          a4 * sc);
            a5 = fmaf(w, __uint_as_float(u.z & 0xFFFF0000u),  a5 * sc);
            a6 = fmaf(w, __uint_as_float(u.w << 16),          a6 * sc);
            a7 = fmaf(w, __uint_as_float(u.w & 0xFFFF0000u),  a7 * sc);
            m = mn;
            p = pn;
        }
    }

    // merge 4 streams: xor16 then xor32
#pragma unroll
    for (int off = 16; off <= 32; off <<= 1) {
        float om  = __shfl_xor(m, off);
        float oden = __shfl_xor(den, off);
        float o0 = __shfl_xor(a0, off), o1 = __shfl_xor(a1, off);
        float o2 = __shfl_xor(a2, off), o3 = __shfl_xor(a3, off);
        float o4 = __shfl_xor(a4, off), o5 = __shfl_xor(a5, off);
        float o6 = __shfl_xor(a6, off), o7 = __shfl_xor(a7, off);
        float M = fmaxf(m, om);
        float fA = __expf(m - M), fB = __expf(om - M);
        den = den * fA + oden * fB;
        a0 = a0 * fA + o0 * fB;  a1 = a1 * fA + o1 * fB;
        a2 = a2 * fA + o2 * fB;  a3 = a3 * fA + o3 * fB;
        a4 = a4 * fA + o4 * fB;  a5 = a5 * fA + o5 * fB;
        a6 = a6 * fA + o6 * fB;  a7 = a7 * fA + o7 * fB;
        m = M;
    }

    if (lane < 16) {
        float inv = 1.f / (den + 1e-16f);
        float4 b0 = ((const float4*)bias)[2 * l16];
        float4 b1v = ((const float4*)bias)[2 * l16 + 1];
        float4 o0v, o1v;
        o0v.x = a0 * inv + b0.x;  o0v.y = a1 * inv + b0.y;
        o0v.z = a2 * inv + b0.z;  o0v.w = a3 * inv + b0.w;
        o1v.x = a4 * inv + b1v.x; o1v.y = a5 * inv + b1v.y;
        o1v.z = a6 * inv + b1v.z; o1v.w = a7 * inv + b1v.w;
        if (x_prev) {
            float4 p0 = ((const float4*)x_prev)[(size_t)d * 32 + 2 * l16];
            float4 p1 = ((const float4*)x_prev)[(size_t)d * 32 + 2 * l16 + 1];
            o0v.x += p0.x; o0v.y += p0.y; o0v.z += p0.z; o0v.w += p0.w;
            o1v.x += p1.x; o1v.y += p1.y; o1v.z += p1.z; o1v.w += p1.w;
        }
        o0v.x = fmaxf(o0v.x, 0.f); o0v.y = fmaxf(o0v.y, 0.f);
        o0v.z = fmaxf(o0v.z, 0.f); o0v.w = fmaxf(o0v.w, 0.f);
        o1v.x = fmaxf(o1v.x, 0.f); o1v.y = fmaxf(o1v.y, 0.f);
        o1v.z = fmaxf(o1v.z, 0.f); o1v.w = fmaxf(o1v.w, 0.f);
        ((float4*)x_out)[(size_t)d * 32 + 2 * l16]     = o0v;
        ((float4*)x_out)[(size_t)d * 32 + 2 * l16 + 1] = o1v;
    }
}

// ---------------------------------------------------------------------------
// MLP head: thread-per-node; x row held as 64 f16x2 regs, W1 pre-packed f16x2
// read wave-uniform (s_load).  v_dot2_f32_f16 with 4 accumulator chains.
__global__ __launch_bounds__(64) void mlp_kernel(
    const float* __restrict__ X, const unsigned* __restrict__ W1h,
    const float* __restrict__ b1, const float* __restrict__ W2,
    const float* __restrict__ b2, float* __restrict__ out, int n) {
    int node = blockIdx.x * 64 + threadIdx.x;
    int r = node < n ? node : n - 1;

    unsigned xh[64];
    const float2* xp = (const float2*)(X + (size_t)r * HCONC);
#pragma unroll
    for (int k2 = 0; k2 < 64; k2++) {
        float2 v = xp[k2];
        __half2 hv = __floats2half2_rn(v.x, v.y);
        xh[k2] = *(unsigned*)&hv;
    }

    float total = b2[0];
    for (int j = 0; j < 100; j++) {
        const unsigned* wr = W1h + j * 64;        // wave-uniform -> s_load
        float p0 = b1[j], p1 = 0.f, p2 = 0.f, p3 = 0.f;
#pragma unroll
        for (int k2 = 0; k2 < 64; k2 += 4) {
            half2_t x0 = __builtin_bit_cast(half2_t, xh[k2 + 0]);
            half2_t x1 = __builtin_bit_cast(half2_t, xh[k2 + 1]);
            half2_t x2 = __builtin_bit_cast(half2_t, xh[k2 + 2]);
            half2_t x3 = __builtin_bit_cast(half2_t, xh[k2 + 3]);
            half2_t w0 = __builtin_bit_cast(half2_t, wr[k2 + 0]);
            half2_t w1 = __builtin_bit_cast(half2_t, wr[k2 + 1]);
            half2_t w2 = __builtin_bit_cast(half2_t, wr[k2 + 2]);
            half2_t w3 = __builtin_bit_cast(half2_t, wr[k2 + 3]);
#if __has_builtin(__builtin_amdgcn_fdot2)
            p0 = __builtin_amdgcn_fdot2(x0, w0, p0, false);
            p1 = __builtin_amdgcn_fdot2(x1, w1, p1, false);
            p2 = __builtin_amdgcn_fdot2(x2, w2, p2, false);
            p3 = __builtin_amdgcn_fdot2(x3, w3, p3, false);
#else
            p0 = fmaf((float)x0[0], (float)w0[0], fmaf((float)x0[1], (float)w0[1], p0));
            p1 = fmaf((float)x1[0], (float)w1[0], fmaf((float)x1[1], (float)w1[1], p1));
            p2 = fmaf((float)x2[0], (float)w2[0], fmaf((float)x2[1], (float)w2[1], p2));
            p3 = fmaf((float)x3[0], (float)w3[0], fmaf((float)x3[1], (float)w3[1], p3));
#endif
        }
        float a = (p0 + p1) + (p2 + p3);
        total = fmaf(fmaxf(a, 0.f), W2[j], total);
    }
    if (node < n) out[node] = 1.f / (1.f + __expf(-total));
}

// ---------------------------------------------------------------------------
extern "C" void kernel_launch(void* const* d_in, const int* in_sizes, int n_in,
                              void* d_out, int out_size, void* d_ws, size_t ws_size,
                              hipStream_t stream) {
    const float* x       = (const float*)d_in[0];
    const int*   ei      = (const int*)d_in[1];     // [2,E]: src then dst
    const int*   etype   = (const int*)d_in[2];
    const float* emb     = (const float*)d_in[3];   // [16,8]
    const float* W_l0    = (const float*)d_in[4];   // [32,128]
    const float* W_l1    = (const float*)d_in[5];   // [128,128]
    const float* W_l2    = (const float*)d_in[6];   // [128,128]
    const float* att_src = (const float*)d_in[7];   // [3,4,32]
    const float* att_dst = (const float*)d_in[8];
    const float* att_edge= (const float*)d_in[9];
    const float* W_edge  = (const float*)d_in[10];  // [3,8,128]
    const float* bias    = (const float*)d_in[11];  // [3,128]
    const float* mW1     = (const float*)d_in[12];  // [128,100]
    const float* mb1     = (const float*)d_in[13];
    const float* mW2     = (const float*)d_in[14];  // [100,1]
    const float* mb2     = (const float*)d_in[15];

    int n = in_sizes[0];   // 50000
    int E = in_sizes[2];   // 800000
    int nbuk = (n + 255) >> 8;   // 196

    // workspace carve
    float* p   = (float*)d_ws;
    float* xa  = p; p += (size_t)n * HCONC;
    float* xb  = p; p += (size_t)n * HCONC;
    float* ssrc = p; p += (size_t)n * NHEAD;
    float* sdst = p; p += (size_t)n * NHEAD;
    float* hbf  = p; p += (size_t)n * 64;          // bf16x2 h buffer (n*128 bf16)
    unsigned* W1h = (unsigned*)p; p += 100 * 64;   // f16x2-packed W1^T
    int* row_ptr     = (int*)p;
    int* gcursor     = row_ptr + n + 1;
    int* bucket_base = gcursor + 256;
    int* cnt         = bucket_base + nbuk + 1;
    float* W0s    = (float*)(cnt + 16);
    float* SA0    = W0s + HCONC;
    float* SD0    = SA0 + NHEAD;
    float* meanat = SD0 + NHEAD;
    float* stab   = meanat + EDIM;   // 3*68 = 204, round to 256
    char* raw = (char*)(stab + 256);
    uint2* ebuf = (uint2*)(((uintptr_t)raw + 15) & ~(uintptr_t)15);  // nbuk*BCAP
    unsigned* col = (unsigned*)(ebuf + (size_t)nbuk * BCAP);         // E entries

    // CSR build: init -> tile counting-sort (binA) -> bucket scan -> fine sort (binB)
    init_kernel<<<1, 256, 0, stream>>>(gcursor, cnt, nbuk);
    binA_kernel<<<(E + TILE - 1) / TILE, 256, 0, stream>>>(ei, etype, E, nbuk,
                                                           gcursor, cnt, ebuf);
    bscan_kernel<<<1, 256, 0, stream>>>(gcursor, nbuk, bucket_base, row_ptr, n);
    binB_kernel<<<nbuk, 256, 0, stream>>>(ebuf, gcursor, bucket_base, n, row_ptr, col);

    setup_kernel<<<1, 256, 0, stream>>>(W_l0, emb, cnt, att_src, att_dst, att_edge, W_edge,
                                        mW1, W0s, SA0, SD0, meanat, stab, W1h, E);

    // layer 0 (rank-1 input)
    l0_kernel<<<(n * 64 + 255) / 256, 256, 0, stream>>>(x, W0s, SA0, SD0,
                                                        (__hip_bfloat162*)hbf, ssrc, sdst, n);
    agg_kernel<<<(n + 3) / 4, 256, 0, stream>>>((const unsigned*)hbf, ssrc, sdst, row_ptr, col,
                                                stab + 0, bias + 0, nullptr, xa, n);
    // layer 1
    transform_kernel<<<(n + 31) / 32, 256, 0, stream>>>(xa, W_l1, att_src + 128, att_dst + 128,
                                                        (__hip_bfloat162*)hbf, ssrc, sdst, n);
    agg_kernel<<<(n + 3) / 4, 256, 0, stream>>>((const unsigned*)hbf, ssrc, sdst, row_ptr, col,
                                                stab + 68, bias + 128, xa, xb, n);
    // layer 2
    transform_kernel<<<(n + 31) / 32, 256, 0, stream>>>(xb, W_l2, att_src + 256, att_dst + 256,
                                                        (__hip_bfloat162*)hbf, ssrc, sdst, n);
    agg_kernel<<<(n + 3) / 4, 256, 0, stream>>>((const unsigned*)hbf, ssrc, sdst, row_ptr, col,
                                                stab + 136, bias + 256, xb, xa, n);
    // MLP head
    mlp_kernel<<<(n + 63) / 64, 64, 0, stream>>>(xa, W1h, mb1, mW2, mb2, (float*)d_out, n);
}